// Round 2
// baseline (873.222 us; speedup 1.0000x reference)
//
#include <hip/hip_runtime.h>

// MinHashSketch: sketch[512,128] = segment_min(x[500000,256] @ H[128,256]^T), empty -> 0
// R4: occupancy/latency probe. BM 128->64: each wave owns 16 rows x 128 cols, one
//     A-fragment (acc 32 VGPRs), __launch_bounds__(256,4) -> 4 waves/SIMD (was 3).
//     Fully unrolled k-loop so A-prefetches can float early under the 128-VGPR cap.
//     Barrier-free main loop (global->reg A, L1/L2-resident fragment-linear B).
//     Epilogue: 64 nodes == 64 lanes, pair-merge removed, same segmented suffix-min.
//     Numerics identical to R2/R3 (4-product split-bf16).

#define M_NODES 500000
#define KDIM    256
#define NHASH   128
#define NSEG    512

#define BM     64
#define BK     32
#define NCHUNK (KDIM / BK)   // 8

typedef __attribute__((ext_vector_type(8))) short bf16x8;
typedef __attribute__((ext_vector_type(4))) float f32x4;

__device__ __forceinline__ unsigned short f2bf(float f) {
    unsigned int u = __float_as_uint(f);
    u += 0x7FFFu + ((u >> 16) & 1u);           // round-to-nearest-even
    return (unsigned short)(u >> 16);
}
__device__ __forceinline__ float bf2f(unsigned short s) {
    return __uint_as_float(((unsigned int)s) << 16);
}
// Order-preserving float->uint encoding: uint-min == float-min
__device__ __forceinline__ unsigned int enc_f(float f) {
    unsigned int b = __float_as_uint(f);
    return (b & 0x80000000u) ? ~b : (b | 0x80000000u);
}

// split 8 fp32 -> bf16 hi + bf16 lo (residual), fragment order
__device__ __forceinline__ void split8(const float4& A, const float4& B,
                                       bf16x8& hi, bf16x8& lo) {
    const unsigned short h0 = f2bf(A.x), h1 = f2bf(A.y), h2 = f2bf(A.z), h3 = f2bf(A.w);
    const unsigned short h4 = f2bf(B.x), h5 = f2bf(B.y), h6 = f2bf(B.z), h7 = f2bf(B.w);
    hi = (bf16x8){(short)h0, (short)h1, (short)h2, (short)h3,
                  (short)h4, (short)h5, (short)h6, (short)h7};
    lo = (bf16x8){(short)f2bf(A.x - bf2f(h0)), (short)f2bf(A.y - bf2f(h1)),
                  (short)f2bf(A.z - bf2f(h2)), (short)f2bf(A.w - bf2f(h3)),
                  (short)f2bf(B.x - bf2f(h4)), (short)f2bf(B.y - bf2f(h5)),
                  (short)f2bf(B.z - bf2f(h6)), (short)f2bf(B.w - bf2f(h7))};
}

// Pre-split H into hi/lo bf16 in MFMA-B-fragment-linear order:
// value B[k][n] = H[n][k]; idx = ((k>>5)*8 + (n>>4))*512 + (((k>>3)&3)*16 + (n&15))*8 + (k&7)
__global__ void hsplit(const float* __restrict__ H,
                       unsigned short* __restrict__ b1f,
                       unsigned short* __restrict__ b2f) {
    const int t = blockIdx.x * 256 + threadIdx.x;   // 32768 elements
    const int n = t >> 8;        // hash row
    const int k = t & 255;
    const float h = H[t];
    const unsigned short s1 = f2bf(h);
    const unsigned short s2 = f2bf(h - bf2f(s1));
    const int idx = ((k >> 5) * 8 + (n >> 4)) * 512 + (((k >> 3) & 3) * 16 + (n & 15)) * 8 + (k & 7);
    b1f[idx] = s1;
    b2f[idx] = s2;
}

__global__ __launch_bounds__(256, 4)
void minhash_main(const float* __restrict__ x,
                  const unsigned int* __restrict__ batch_raw,
                  const unsigned short* __restrict__ b1f,
                  const unsigned short* __restrict__ b2f,
                  unsigned int* __restrict__ ws) {
    __shared__ __align__(16) float sc[64 * 68];     // 17.4 KB, epilogue only

    const int tid  = threadIdx.x;
    const int lane = tid & 63;
    const int w    = __builtin_amdgcn_readfirstlane(tid >> 6);  // wave 0..3
    const int quad = lane >> 4;
    const int c16  = lane & 15;
    const long long blockBase = (long long)blockIdx.x * BM;

    // wave w owns rows [w*16, w*16+16), all 128 cols
    const long long r0 = blockBase + w * 16 + c16;
    const bool g0 = r0 < (long long)M_NODES;
    const float* pa0 = x + r0 * KDIM + quad * 8;

    f32x4 acc[8];
    #pragma unroll
    for (int nt = 0; nt < 8; ++nt)
        acc[nt] = (f32x4){0.f, 0.f, 0.f, 0.f};

    const float4 z4 = make_float4(0.f, 0.f, 0.f, 0.f);
    // software-pipelined A prefetch (compiler may deepen under full unroll)
    float4 n0a = g0 ? *(const float4*)(pa0)     : z4;
    float4 n0b = g0 ? *(const float4*)(pa0 + 4) : z4;

    const unsigned short* gb1 = b1f + lane * 8;
    const unsigned short* gb2 = b2f + lane * 8;

    #pragma unroll
    for (int chunk = 0; chunk < NCHUNK; ++chunk) {
        const float4 c0a = n0a, c0b = n0b;
        if (chunk < NCHUNK - 1) {
            const int o = (chunk + 1) * BK;
            n0a = g0 ? *(const float4*)(pa0 + o)     : z4;
            n0b = g0 ? *(const float4*)(pa0 + o + 4) : z4;
        }
        bf16x8 a1, a2;
        split8(c0a, c0b, a1, a2);

        const unsigned short* cb1 = gb1 + chunk * 4096;
        const unsigned short* cb2 = gb2 + chunk * 4096;
        #pragma unroll
        for (int nt = 0; nt < 8; ++nt) {
            const bf16x8 b1v = *(const bf16x8*)(cb1 + nt * 512);
            const bf16x8 b2v = *(const bf16x8*)(cb2 + nt * 512);
            acc[nt] = __builtin_amdgcn_mfma_f32_16x16x32_bf16(a1, b1v, acc[nt], 0, 0, 0);
            acc[nt] = __builtin_amdgcn_mfma_f32_16x16x32_bf16(a2, b1v, acc[nt], 0, 0, 0);
            acc[nt] = __builtin_amdgcn_mfma_f32_16x16x32_bf16(a1, b2v, acc[nt], 0, 0, 0);
            acc[nt] = __builtin_amdgcn_mfma_f32_16x16x32_bf16(a2, b2v, acc[nt], 0, 0, 0);
        }
    }

    // ---- epilogue: 64 nodes == 64 lanes, segmented suffix-min ----
    // batch dtype sniff: int64 -> word[499999] is high half of elem 249999 (==0);
    // int32 -> word[499999] == batch[499999] (sorted, ~511, nonzero).
    const bool is64 = (batch_raw[499999] == 0u);
    const long long* bb64 = (const long long*)batch_raw;
    const int*       bb32 = (const int*)batch_raw;

    const long long gn = blockBase + lane;
    int seg = -1;
    if (gn < (long long)M_NODES) seg = is64 ? (int)bb64[gn] : bb32[gn];

    #pragma unroll
    for (int h = 0; h < 2; ++h) {
        // C layout: col = c16 (+16*ct), row = quad*4 + reg -> node = w*16 + quad*4
        #pragma unroll
        for (int ct = 0; ct < 4; ++ct) {
            const int colp = ct * 16 + c16;
            const int node = w * 16 + quad * 4;
            *(f32x4*)(sc + colp * 68 + node) = acc[h * 4 + ct];
        }
        __syncthreads();

        // wave w reduces its 16-col group over all 64 nodes
        float v[16];
        #pragma unroll
        for (int j = 0; j < 16; ++j)
            v[j] = sc[(w * 16 + j) * 68 + lane];

        #pragma unroll
        for (int d = 1; d < 64; d <<= 1) {
            const int  oseg = __shfl_down(seg, d, 64);
            const bool ok   = (lane + d < 64) && (oseg == seg);
            #pragma unroll
            for (int j = 0; j < 16; ++j) {
                const float ov = __shfl_down(v[j], d, 64);
                if (ok) v[j] = fminf(v[j], ov);
            }
        }
        const int pseg = __shfl_up(seg, 1, 64);
        if (seg >= 0 && (lane == 0 || pseg != seg)) {
            #pragma unroll
            for (int j = 0; j < 16; ++j)
                atomicMin(&ws[seg * NHASH + h * 64 + w * 16 + j], enc_f(v[j]));
        }
        __syncthreads();
    }
}

__global__ void minhash_finalize(const unsigned int* __restrict__ ws,
                                 float* __restrict__ out) {
    const int i = blockIdx.x * blockDim.x + threadIdx.x;
    if (i < NSEG * NHASH) {
        const unsigned int u = ws[i];
        out[i] = (u == 0xFFFFFFFFu)
                     ? 0.0f   // untouched sentinel == empty segment
                     : ((u & 0x80000000u) ? __uint_as_float(u ^ 0x80000000u)
                                          : __uint_as_float(~u));
    }
}

extern "C" void kernel_launch(void* const* d_in, const int* in_sizes, int n_in,
                              void* d_out, int out_size, void* d_ws, size_t ws_size,
                              hipStream_t stream) {
    const float* x = (const float*)d_in[0];
    const unsigned int* batch = (const unsigned int*)d_in[1];
    const float* H = (const float*)d_in[3];

    unsigned int*   ws  = (unsigned int*)d_ws;
    unsigned short* b1f = (unsigned short*)((char*)d_ws + 256 * 1024);
    unsigned short* b2f = (unsigned short*)((char*)d_ws + 320 * 1024);

    hipMemsetAsync(d_ws, 0xFF, NSEG * NHASH * sizeof(unsigned int), stream);
    hsplit<<<(KDIM * NHASH) / 256, 256, 0, stream>>>(H, b1f, b2f);

    const int grid = (M_NODES + BM - 1) / BM;  // 7813
    minhash_main<<<grid, 256, 0, stream>>>(x, batch, b1f, b2f, ws);
    minhash_finalize<<<(NSEG * NHASH + 255) / 256, 256, 0, stream>>>(ws, (float*)d_out);
}

// Round 3
// 715.256 us; speedup vs baseline: 1.2209x; 1.2209x over previous
//
#include <hip/hip_runtime.h>

// MinHashSketch: sketch[512,128] = segment_min(x[500000,256] @ H[128,256]^T), empty -> 0
// R5: R2 dataflow (coalesced fp32 A -> split-bf16 -> frag-linear LDS; B shared via LDS)
//     + continuous-stream pipeline: B staged by global_load_lds (dbuf), A(c+1) fp32
//     loads issued during stage(c) and kept in flight across RAW s_barriers (no
//     vmcnt(0) at barriers; only lgkmcnt(0) per ISA). One stage + one compute phase
//     per chunk; HBM never idles per block. Numerics identical (4-product split-bf16).
//     Epilogue = R2's proven wave segmented suffix-min.

#define M_NODES 500000
#define KDIM    256
#define NHASH   128
#define NSEG    512

#define BM     128
#define BK     32
#define NCHUNK (KDIM / BK)   // 8

typedef __attribute__((ext_vector_type(8))) short bf16x8;
typedef __attribute__((ext_vector_type(4))) float f32x4;

__device__ __forceinline__ unsigned short f2bf(float f) {
    unsigned int u = __float_as_uint(f);
    u += 0x7FFFu + ((u >> 16) & 1u);           // round-to-nearest-even
    return (unsigned short)(u >> 16);
}
__device__ __forceinline__ float bf2f(unsigned short s) {
    return __uint_as_float(((unsigned int)s) << 16);
}
// Order-preserving float->uint encoding: uint-min == float-min
__device__ __forceinline__ unsigned int enc_f(float f) {
    unsigned int b = __float_as_uint(f);
    return (b & 0x80000000u) ? ~b : (b | 0x80000000u);
}

// Pre-split H into hi/lo bf16 in MFMA-B-fragment-linear order:
// value B[k][n] = H[n][k]; idx = ((k>>5)*8 + (n>>4))*512 + (((k>>3)&3)*16 + (n&15))*8 + (k&7)
__global__ void hsplit(const float* __restrict__ H,
                       unsigned short* __restrict__ b1f,
                       unsigned short* __restrict__ b2f) {
    const int t = blockIdx.x * 256 + threadIdx.x;   // 32768 elements
    const int n = t >> 8;        // hash row
    const int k = t & 255;
    const float h = H[t];
    const unsigned short s1 = f2bf(h);
    const unsigned short s2 = f2bf(h - bf2f(s1));
    const int idx = ((k >> 5) * 8 + (n >> 4)) * 512 + (((k >> 3) & 3) * 16 + (n & 15)) * 8 + (k & 7);
    b1f[idx] = s1;
    b2f[idx] = s2;
}

// LDS A layout: tile T=row>>4 (0..7): T*576 + kg*144 + (row&15)*8 + j   (kg=k>>3 in chunk)
#define ATILE 576
#define AKG   144

// raw barrier: waits own LDS ops only; leaves VMEM (A prefetch + glds B) in flight
__device__ __forceinline__ void barrier_lgkm() {
    __builtin_amdgcn_sched_barrier(0);
    asm volatile("s_waitcnt lgkmcnt(0)" ::: "memory");
    __builtin_amdgcn_s_barrier();
    __builtin_amdgcn_sched_barrier(0);
}

__global__ __launch_bounds__(256, 3)
void minhash_main(const float* __restrict__ x,
                  const unsigned int* __restrict__ batch_raw,
                  const unsigned short* __restrict__ b1f,
                  const unsigned short* __restrict__ b2f,
                  unsigned int* __restrict__ ws) {
    // 51200 B: a1 9216 | a2 9216 | B dbuf 2 x (b1 8KB + b2 8KB)
    __shared__ __align__(16) char smem[51200];
    unsigned short* a1 = (unsigned short*)smem;                 // 4608 shorts
    unsigned short* a2 = a1 + 4608;
    unsigned short* bb = a1 + 9216;                             // 2 x 8192 shorts
    float* sc = (float*)smem;                                   // epilogue scratch 64x132 f32

    const int tid  = threadIdx.x;
    const int lane = tid & 63;
    const int w    = __builtin_amdgcn_readfirstlane(tid >> 6);  // wave 0..3
    const int quad = lane >> 4;
    const int c16  = lane & 15;
    const int rh   = w & 1;       // row-half (64 rows)
    const int ch   = w >> 1;      // col-half (64 cols)
    const long long blockBase = (long long)blockIdx.x * BM;

    const int arow = tid >> 3;    // staging row 0..31 (+pass*32)
    const int f4   = tid & 7;     // float4 slot in 32-k chunk

    f32x4 acc[4][4];
    #pragma unroll
    for (int rt = 0; rt < 4; ++rt)
        #pragma unroll
        for (int ct = 0; ct < 4; ++ct)
            acc[rt][ct] = (f32x4){0.f, 0.f, 0.f, 0.f};

    const float4 z4 = make_float4(0.f, 0.f, 0.f, 0.f);

    // ---- prologue: issue glds B(0) -> buf0, A(0) fp32 loads -> regs ----
    #pragma unroll
    for (int s = 0; s < 2; ++s)
        #pragma unroll
        for (int j = 0; j < 2; ++j) {
            const unsigned short* src = (s ? b2f : b1f) + (w * 2 + j) * 512 + lane * 8;
            unsigned short* dst = bb + s * 4096 + (w * 2 + j) * 512;
            __builtin_amdgcn_global_load_lds(
                (const __attribute__((address_space(1))) unsigned int*)src,
                (__attribute__((address_space(3))) unsigned int*)dst, 16, 0, 0);
        }
    float4 av[4];
    #pragma unroll
    for (int p = 0; p < 4; ++p) {
        const long long gr = blockBase + arow + p * 32;
        av[p] = (gr < (long long)M_NODES) ? *(const float4*)(x + gr * KDIM + f4 * 4) : z4;
    }

    for (int c = 0; c < NCHUNK; ++c) {
        // ---- [S] convert + write A(c) (compiler's vmcnt wait on av drains glds B(c) too, FIFO) ----
        #pragma unroll
        for (int p = 0; p < 4; ++p) {
            const int r = arow + p * 32;
            const float4 vv = av[p];
            const unsigned short h1x = f2bf(vv.x), h1y = f2bf(vv.y),
                                 h1z = f2bf(vv.z), h1w = f2bf(vv.w);
            const unsigned short l1x = f2bf(vv.x - bf2f(h1x)), l1y = f2bf(vv.y - bf2f(h1y)),
                                 l1z = f2bf(vv.z - bf2f(h1z)), l1w = f2bf(vv.w - bf2f(h1w));
            const int base = (r >> 4) * ATILE + (f4 >> 1) * AKG + (r & 15) * 8 + (f4 & 1) * 4;
            uint2 p1, p2;
            p1.x = (unsigned)h1x | ((unsigned)h1y << 16);
            p1.y = (unsigned)h1z | ((unsigned)h1w << 16);
            p2.x = (unsigned)l1x | ((unsigned)l1y << 16);
            p2.y = (unsigned)l1z | ((unsigned)l1w << 16);
            *(uint2*)(a1 + base) = p1;
            *(uint2*)(a2 + base) = p2;
        }
        // issue next chunk's B glds + A fp32 loads (stay in flight across both barriers)
        if (c < NCHUNK - 1) {
            const int cn = c + 1;
            #pragma unroll
            for (int s = 0; s < 2; ++s)
                #pragma unroll
                for (int j = 0; j < 2; ++j) {
                    const unsigned short* src = (s ? b2f : b1f) + cn * 4096 + (w * 2 + j) * 512 + lane * 8;
                    unsigned short* dst = bb + (cn & 1) * 8192 + s * 4096 + (w * 2 + j) * 512;
                    __builtin_amdgcn_global_load_lds(
                        (const __attribute__((address_space(1))) unsigned int*)src,
                        (__attribute__((address_space(3))) unsigned int*)dst, 16, 0, 0);
                }
            #pragma unroll
            for (int p = 0; p < 4; ++p) {
                const long long gr = blockBase + arow + p * 32;
                av[p] = (gr < (long long)M_NODES)
                            ? *(const float4*)(x + gr * KDIM + cn * BK + f4 * 4) : z4;
            }
        }
        barrier_lgkm();   // bar1: A(c) writes visible; glds B(c) done (drained above, all waves)

        // ---- [C] MFMA on chunk c ----
        bf16x8 a1f[4], a2f[4];
        #pragma unroll
        for (int rt = 0; rt < 4; ++rt) {
            const int off = (rh * 4 + rt) * ATILE + quad * AKG + c16 * 8;
            a1f[rt] = *(const bf16x8*)(a1 + off);
            a2f[rt] = *(const bf16x8*)(a2 + off);
        }
        const unsigned short* bcur = bb + (c & 1) * 8192;
        #pragma unroll
        for (int ct = 0; ct < 4; ++ct) {
            const int boff = ((ch * 4 + ct) * 64 + lane) * 8;
            const bf16x8 b1v = *(const bf16x8*)(bcur + boff);
            const bf16x8 b2v = *(const bf16x8*)(bcur + 4096 + boff);
            #pragma unroll
            for (int rt = 0; rt < 4; ++rt) {
                acc[rt][ct] = __builtin_amdgcn_mfma_f32_16x16x32_bf16(a1f[rt], b1v, acc[rt][ct], 0, 0, 0);
                acc[rt][ct] = __builtin_amdgcn_mfma_f32_16x16x32_bf16(a2f[rt], b1v, acc[rt][ct], 0, 0, 0);
                acc[rt][ct] = __builtin_amdgcn_mfma_f32_16x16x32_bf16(a1f[rt], b2v, acc[rt][ct], 0, 0, 0);
                acc[rt][ct] = __builtin_amdgcn_mfma_f32_16x16x32_bf16(a2f[rt], b2v, acc[rt][ct], 0, 0, 0);
            }
        }
        barrier_lgkm();   // bar2: all reads of A-buf and B-buf[c&1] done -> next stage may overwrite
    }

    // ---- epilogue: segment ids for this lane's node pair (reduction mapping) ----
    // batch dtype sniff: int64 -> word[499999] is high half of elem 249999 (==0);
    // int32 -> word[499999] == batch[499999] (sorted, ~511, nonzero).
    const bool is64 = (batch_raw[499999] == 0u);
    const long long* bb64 = (const long long*)batch_raw;
    const int*       bb32 = (const int*)batch_raw;

    const int p = lane;                // node-pair index: nodes 2p, 2p+1 (block-rel)
    const int cg = w;                  // col-group within the 64-col half
    const long long gn0 = blockBase + 2 * p;
    const long long gn1 = gn0 + 1;
    int seg0 = -1, seg1 = -1;
    if (gn0 < (long long)M_NODES) seg0 = is64 ? (int)bb64[gn0] : bb32[gn0];
    if (gn1 < (long long)M_NODES) seg1 = is64 ? (int)bb64[gn1] : bb32[gn1];

    for (int h = 0; h < 2; ++h) {
        // waves holding this col-half write acc to sc[col'][node], stride 132
        if (ch == h) {
            #pragma unroll
            for (int ct = 0; ct < 4; ++ct) {
                #pragma unroll
                for (int rt = 0; rt < 4; ++rt) {
                    const int node = rh * 64 + rt * 16 + quad * 4;
                    const int colp = ct * 16 + c16;
                    *(f32x4*)(sc + colp * 132 + node) = acc[rt][ct];
                }
            }
        }
        __syncthreads();

        // pair-merge + wave segmented suffix-min over 64 node-pairs
        float v[16];
        int seg;
        if (seg0 == seg1) {
            seg = seg0;
            #pragma unroll
            for (int j = 0; j < 16; ++j) {
                const float2 nv = *(const float2*)(sc + (cg * 16 + j) * 132 + 2 * p);
                v[j] = fminf(nv.x, nv.y);
            }
        } else {
            seg = seg1;
            #pragma unroll
            for (int j = 0; j < 16; ++j) {
                const float2 nv = *(const float2*)(sc + (cg * 16 + j) * 132 + 2 * p);
                if (seg0 >= 0)
                    atomicMin(&ws[seg0 * NHASH + h * 64 + cg * 16 + j], enc_f(nv.x));
                v[j] = nv.y;
            }
        }
        #pragma unroll
        for (int d = 1; d < 64; d <<= 1) {
            const int  oseg = __shfl_down(seg, d, 64);
            const bool ok   = (lane + d < 64) && (oseg == seg);
            #pragma unroll
            for (int j = 0; j < 16; ++j) {
                const float ov = __shfl_down(v[j], d, 64);
                if (ok) v[j] = fminf(v[j], ov);
            }
        }
        const int pseg = __shfl_up(seg, 1, 64);
        if (seg >= 0 && (lane == 0 || pseg != seg)) {
            #pragma unroll
            for (int j = 0; j < 16; ++j)
                atomicMin(&ws[seg * NHASH + h * 64 + cg * 16 + j], enc_f(v[j]));
        }
        __syncthreads();
    }
}

__global__ void minhash_finalize(const unsigned int* __restrict__ ws,
                                 float* __restrict__ out) {
    const int i = blockIdx.x * blockDim.x + threadIdx.x;
    if (i < NSEG * NHASH) {
        const unsigned int u = ws[i];
        out[i] = (u == 0xFFFFFFFFu)
                     ? 0.0f   // untouched sentinel == empty segment
                     : ((u & 0x80000000u) ? __uint_as_float(u ^ 0x80000000u)
                                          : __uint_as_float(~u));
    }
}

extern "C" void kernel_launch(void* const* d_in, const int* in_sizes, int n_in,
                              void* d_out, int out_size, void* d_ws, size_t ws_size,
                              hipStream_t stream) {
    const float* x = (const float*)d_in[0];
    const unsigned int* batch = (const unsigned int*)d_in[1];
    const float* H = (const float*)d_in[3];

    unsigned int*   ws  = (unsigned int*)d_ws;
    unsigned short* b1f = (unsigned short*)((char*)d_ws + 256 * 1024);
    unsigned short* b2f = (unsigned short*)((char*)d_ws + 320 * 1024);

    hipMemsetAsync(d_ws, 0xFF, NSEG * NHASH * sizeof(unsigned int), stream);
    hsplit<<<(KDIM * NHASH) / 256, 256, 0, stream>>>(H, b1f, b2f);

    const int grid = (M_NODES + BM - 1) / BM;  // 3907
    minhash_main<<<grid, 256, 0, stream>>>(x, batch, b1f, b2f, ws);
    minhash_finalize<<<(NSEG * NHASH + 255) / 256, 256, 0, stream>>>(ws, (float*)d_out);
}